// Round 9
// baseline (2895.307 us; speedup 1.0000x reference)
//
#include <hip/hip_runtime.h>
#include <math.h>

namespace {

typedef __fp16 half2v __attribute__((ext_vector_type(2)));
static_assert(sizeof(half2v) == 4, "half2v must be 32-bit");

constexpr int T = 4096, NB = 256, I = 64, H = 256, O = 64;
constexpr int WSTRIDE = 12;                 // words per kq group: 8 data + 4 pad (16B-aligned, <=2-way banks)
constexpr int HWORDS  = 15 * WSTRIDE + 8;   // 188 words per h buffer

__device__ __forceinline__ half2v pkrtz(float a, float b) {
  return __builtin_bit_cast(half2v, __builtin_amdgcn_cvt_pkrtz(a, b));
}

__device__ __forceinline__ float fdot2(half2v a, half2v b, float c) {
  typedef _Float16 fdot_t __attribute__((ext_vector_type(2)));
  return __builtin_amdgcn_fdot2(__builtin_bit_cast(fdot_t, a),
                                __builtin_bit_cast(fdot_t, b), c, false);
}

// 16-lane-row sum via DPP row rotations. BUILTIN form only (R6 lesson:
// inline-asm DPP chains violate the VALU->DPP wait-state rules).
template <int CTRL>
__device__ __forceinline__ float ror_add(float v) {
  int r = __builtin_amdgcn_update_dpp(0, __float_as_int(v), CTRL, 0xF, 0xF, true);
  return v + __int_as_float(r);
}
__device__ __forceinline__ float red16(float v) {
  v = ror_add<0x121>(v);  // row_ror:1
  v = ror_add<0x122>(v);  // row_ror:2
  v = ror_add<0x124>(v);  // row_ror:4
  v = ror_add<0x128>(v);  // row_ror:8
  return v;
}

// 1024 threads/block, one block per batch row, one barrier per step.
// kq = tid&15 owns k-range [kq*16, kq*16+16); jg = tid>>4 owns h-rows
// jg*4..+3 and y-row jg. Weights live as 48 half2 regs. h is stored in LDS
// as half2 words (word W = (h[2W], h[2W+1])) at index (W>>3)*WSTRIDE+(W&7).
//
// amdgpu_waves_per_eu(4,4): grid = 256 blocks = exactly 1 block/CU, so real
// occupancy is structurally 16 waves/CU (4/SIMD). Without this, the
// allocator targets 2 blocks/CU -> caps arch VGPRs at 64 (observed
// VGPR_Count=56 in R4/R7/R8) -> parks the 48 weight regs in AGPRs ->
// ~48 phantom v_accvgpr_reads per step (the measured 2x VALU inflation).
__global__ __launch_bounds__(1024)
__attribute__((amdgpu_waves_per_eu(4, 4))) void rnn_fused(
    const float* __restrict__ xin,   // [T,NB,I]
    const float* __restrict__ Wih,   // [H,I]
    const float* __restrict__ Whh,   // [H,H]
    const float* __restrict__ Who,   // [O,H]
    float* __restrict__ out)         // [T*NB*O] ++ [NB*H]
{
  const int b   = blockIdx.x;
  const int tid = threadIdx.x;
  const int kq  = tid & 15;
  const int jg  = tid >> 4;
  const bool kb1 = (kq & 1) != 0;
  const bool kb2 = (kq & 2) != 0;

  __shared__ __align__(16) uint32_t hbuf[2][HWORDS];

  // ---- resident weights as half2 (48 regs) ----
  half2v whhp[32];
#pragma unroll
  for (int jj = 0; jj < 4; ++jj) {
    const float* r = Whh + (size_t)(jg * 4 + jj) * H + kq * 16;
#pragma unroll
    for (int c = 0; c < 4; ++c) {
      float4 v = *reinterpret_cast<const float4*>(r + c * 4);
      whhp[jj * 8 + c * 2]     = pkrtz(v.x, v.y);
      whhp[jj * 8 + c * 2 + 1] = pkrtz(v.z, v.w);
    }
  }
  half2v wihp[8];
#pragma unroll
  for (int jj = 0; jj < 4; ++jj) {
    float4 v = *reinterpret_cast<const float4*>(Wih + (size_t)(jg * 4 + jj) * I + kq * 4);
    wihp[jj * 2]     = pkrtz(v.x, v.y);
    wihp[jj * 2 + 1] = pkrtz(v.z, v.w);
  }
  half2v whop[8];
  {
    const float* r = Who + (size_t)jg * H + kq * 16;
#pragma unroll
    for (int c = 0; c < 4; ++c) {
      float4 v = *reinterpret_cast<const float4*>(r + c * 4);
      whop[c * 2]     = pkrtz(v.x, v.y);
      whop[c * 2 + 1] = pkrtz(v.z, v.w);
    }
  }

  // ---- init ----
  if (tid < HWORDS) hbuf[0][tid] = 0u;               // h(-1) = 0
  const float* xg = xin + (size_t)b * I + kq * 4;    // + t*16384 floats
  float4 xrA = *reinterpret_cast<const float4*>(xg); // x(0)
  float4 xrB;
  // odd lanes write h-pair word W = jg*2 + ((kq&3)>>1)
  const int Wl    = jg * 2 + ((kq & 3) >> 1);
  const int wword = (Wl >> 3) * WSTRIDE + (Wl & 7);
  __syncthreads();

#define STEP(SRC, DST, TCUR, XCUR, XNXT, TPRE)                                   \
  {                                                                              \
    const uint4* rp_ = reinterpret_cast<const uint4*>((SRC) + kq * WSTRIDE);     \
    uint4 w0_ = rp_[0];                                                          \
    uint4 w1_ = rp_[1];                                                          \
    XNXT = *reinterpret_cast<const float4*>(xg + ((size_t)(TPRE) << 14));        \
    half2v xp0_ = pkrtz(XCUR.x, XCUR.y);                                         \
    half2v xp1_ = pkrtz(XCUR.z, XCUR.w);                                         \
    float a0_ = fdot2(xp1_, wihp[1], fdot2(xp0_, wihp[0], 0.f));                 \
    float a1_ = fdot2(xp1_, wihp[3], fdot2(xp0_, wihp[2], 0.f));                 \
    float a2_ = fdot2(xp1_, wihp[5], fdot2(xp0_, wihp[4], 0.f));                 \
    float a3_ = fdot2(xp1_, wihp[7], fdot2(xp0_, wihp[6], 0.f));                 \
    float ay_ = 0.f;                                                             \
    half2v hk_[8];                                                               \
    hk_[0] = __builtin_bit_cast(half2v, w0_.x);                                  \
    hk_[1] = __builtin_bit_cast(half2v, w0_.y);                                  \
    hk_[2] = __builtin_bit_cast(half2v, w0_.z);                                  \
    hk_[3] = __builtin_bit_cast(half2v, w0_.w);                                  \
    hk_[4] = __builtin_bit_cast(half2v, w1_.x);                                  \
    hk_[5] = __builtin_bit_cast(half2v, w1_.y);                                  \
    hk_[6] = __builtin_bit_cast(half2v, w1_.z);                                  \
    hk_[7] = __builtin_bit_cast(half2v, w1_.w);                                  \
    _Pragma("unroll")                                                            \
    for (int c = 0; c < 8; ++c) {                                                \
      a0_ = fdot2(hk_[c], whhp[c], a0_);                                         \
      a1_ = fdot2(hk_[c], whhp[8 + c], a1_);                                     \
      a2_ = fdot2(hk_[c], whhp[16 + c], a2_);                                    \
      a3_ = fdot2(hk_[c], whhp[24 + c], a3_);                                    \
      ay_ = fdot2(hk_[c], whop[c], ay_);                                         \
    }                                                                            \
    a0_ = red16(a0_); a1_ = red16(a1_);                                          \
    a2_ = red16(a2_); a3_ = red16(a3_);                                          \
    ay_ = red16(ay_);                                                            \
    float hs_ = kb2 ? (kb1 ? a3_ : a2_) : (kb1 ? a1_ : a0_);                     \
    float e_  = __builtin_amdgcn_exp2f(hs_ * 2.885390081777927f);                \
    float hv_ = fmaf(-2.f, __builtin_amdgcn_rcpf(e_ + 1.f), 1.f);                \
    float nb_ = __int_as_float(__builtin_amdgcn_mov_dpp(                         \
        __float_as_int(hv_), 0x121, 0xF, 0xF, false));                           \
    half2v pk_ = pkrtz(nb_, hv_);                                                \
    if (kb1) (DST)[wword] = __builtin_bit_cast(uint32_t, pk_);                   \
    if (kq == 0 && (TCUR) > 0)                                                   \
      out[((size_t)((TCUR) - 1) * NB + b) * O + jg] = ay_;                       \
    asm volatile("s_waitcnt lgkmcnt(0)\n\ts_barrier" ::: "memory");              \
  }

  for (int t = 0; t < T; t += 2) {
    const int tp = (t + 3 < T) ? (t + 2) : (T - 1);
    STEP(hbuf[0], hbuf[1], t, xrA, xrB, t + 1);
    STEP(hbuf[1], hbuf[0], t + 1, xrB, xrA, tp);
  }
#undef STEP

  // ---- epilogue: y(T-1) from h(T-1) in hbuf[0] ----
  {
    const uint4* rp = reinterpret_cast<const uint4*>(&hbuf[0][kq * WSTRIDE]);
    uint4 w0 = rp[0], w1 = rp[1];
    half2v hk[8];
    hk[0] = __builtin_bit_cast(half2v, w0.x);
    hk[1] = __builtin_bit_cast(half2v, w0.y);
    hk[2] = __builtin_bit_cast(half2v, w0.z);
    hk[3] = __builtin_bit_cast(half2v, w0.w);
    hk[4] = __builtin_bit_cast(half2v, w1.x);
    hk[5] = __builtin_bit_cast(half2v, w1.y);
    hk[6] = __builtin_bit_cast(half2v, w1.z);
    hk[7] = __builtin_bit_cast(half2v, w1.w);
    float ay = 0.f;
#pragma unroll
    for (int c = 0; c < 8; ++c) ay = fdot2(hk[c], whop[c], ay);
    ay = red16(ay);
    if (kq == 0) out[((size_t)(T - 1) * NB + b) * O + jg] = ay;
  }
  // ---- h_last (fp32) ----
  if (tid < 128) {
    uint32_t w = hbuf[0][(tid >> 3) * WSTRIDE + (tid & 7)];
    half2v hh = __builtin_bit_cast(half2v, w);
    float* hl = out + (size_t)T * NB * O + (size_t)b * H + 2 * tid;
    hl[0] = (float)hh.x;
    hl[1] = (float)hh.y;
  }
}

}  // namespace

extern "C" void kernel_launch(void* const* d_in, const int* in_sizes, int n_in,
                              void* d_out, int out_size, void* d_ws, size_t ws_size,
                              hipStream_t stream) {
  const float* xin = (const float*)d_in[0];
  const float* Wih = (const float*)d_in[1];
  const float* Whh = (const float*)d_in[2];
  const float* Who = (const float*)d_in[3];
  float* out = (float*)d_out;
  hipLaunchKernelGGL(rnn_fused, dim3(NB), dim3(1024), 0, stream,
                     xin, Wih, Whh, Who, out);
}